// Round 20
// baseline (446.430 us; speedup 1.0000x reference)
//
#include <hip/hip_runtime.h>

typedef unsigned short u16;
typedef _Float16 f16x8 __attribute__((ext_vector_type(8)));
typedef float f32x4 __attribute__((ext_vector_type(4)));
typedef u16 u16x8 __attribute__((ext_vector_type(8)));

#define MINF (-0x1.fffffep+127f)
#define SCALE 0.08838834764831845f

__device__ __forceinline__ u16 f2h(float f) {
    _Float16 h = (_Float16)f;
    return __builtin_bit_cast(u16, h);
}
__device__ __forceinline__ float h2f(u16 u) {
    _Float16 h = __builtin_bit_cast(_Float16, u);
    return (float)h;
}

typedef const __attribute__((address_space(1))) void* gptr_t;
typedef __attribute__((address_space(3))) void* sptr_t;
#define GLDS16(g, l) __builtin_amdgcn_global_load_lds((gptr_t)(const void*)(g), (sptr_t)(void*)(l), 16, 0, 0)

// ---------------- f32 -> f16 conversion, 8 elem/thread (n must be divisible by 2048) ----------------
__global__ void convk8(const float* __restrict__ in, u16* __restrict__ out, int n) {
    int i = (blockIdx.x * 256 + threadIdx.x) * 8;
    if (i >= n) return;
    f32x4 a = *(const f32x4*)&in[i];
    f32x4 b = *(const f32x4*)&in[i + 4];
    u16x8 r;
#pragma unroll
    for (int j = 0; j < 4; ++j) { r[j] = f2h(a[j]); r[j + 4] = f2h(b[j]); }
    *(u16x8*)&out[i] = r;
}

// ---------------- fused Wq/Wk/Wv -> f16 into contiguous wbf ----------------
__global__ void convw3(const float* __restrict__ Wq, const float* __restrict__ Wk,
                       const float* __restrict__ Wv, u16* __restrict__ out) {
    int i = (blockIdx.x * 256 + threadIdx.x) * 8;
    const float* src;
    int off;
    if (i < 4194304) { src = Wq; off = i; }
    else if (i < 6291456) { src = Wk; off = i - 4194304; }
    else { src = Wv; off = i - 6291456; }
    f32x4 a = *(const f32x4*)&src[off];
    f32x4 b = *(const f32x4*)&src[off + 4];
    u16x8 r;
#pragma unroll
    for (int j = 0; j < 4; ++j) { r[j] = f2h(a[j]); r[j + 4] = f2h(b[j]); }
    *(u16x8*)&out[i] = r;
}

// ---------------- QKV GEMM, 256x256 tile, BK=64, 8 waves, counted-vmcnt + XCD swizzle ----------------
__global__ __launch_bounds__(512, 1) void gemm8_qkv(
    const u16* __restrict__ A, const u16* __restrict__ Bw,
    u16* __restrict__ qo, u16* __restrict__ ko, u16* __restrict__ vto) {
    __shared__ alignas(16) u16 AS[2][2][128 * 64];
    __shared__ alignas(16) u16 BS[2][2][128 * 64];
    const int K = 2048, NT = 32;
    int tid = threadIdx.x;
    int wid = tid >> 6, lane = tid & 63;
    int l16 = lane & 15, lhi = lane >> 4;
    int wm = wid >> 2, wn = wid & 3;
    int bid = blockIdx.y * 16 + blockIdx.x;
    int swz = (bid & 7) * 32 + (bid >> 3);
    int bm = (swz >> 4) * 256, bn = (swz & 15) * 256;
    int srow = lane >> 3;
    int schunk = (lane & 7) ^ srow;
    f32x4 acc[8][4] = {};

    auto STAGE = [&](int t, int buf) {
        int kt = t * 64;
#pragma unroll
        for (int i = 0; i < 2; ++i) {
            int c = wid * 2 + i;
            int row = c * 8 + srow;
            const u16* sa0 = A + (size_t)(bm + row) * K + kt + schunk * 8;
            GLDS16(sa0, &AS[buf][0][c * 512]);
            const u16* sa1 = A + (size_t)(bm + 128 + row) * K + kt + schunk * 8;
            GLDS16(sa1, &AS[buf][1][c * 512]);
            const u16* sb0 = Bw + (size_t)(bn + row) * K + kt + schunk * 8;
            GLDS16(sb0, &BS[buf][0][c * 512]);
            const u16* sb1 = Bw + (size_t)(bn + 128 + row) * K + kt + schunk * 8;
            GLDS16(sb1, &BS[buf][1][c * 512]);
        }
    };

    auto COMPUTE = [&](int buf) {
#pragma unroll
        for (int kk = 0; kk < 2; ++kk) {
            f16x8 af[8], bf[4];
#pragma unroll
            for (int ni = 0; ni < 4; ++ni) {
                int rb = wn * 64 + ni * 16 + l16;
                int half = rb >> 7, rh = rb & 127;
                int c2 = (kk * 4 + lhi) ^ (rh & 7);
                bf[ni] = *(const f16x8*)&BS[buf][half][rh * 64 + c2 * 8];
            }
#pragma unroll
            for (int mi = 0; mi < 8; ++mi) {
                int rh = mi * 16 + l16;
                int c2 = (kk * 4 + lhi) ^ (rh & 7);
                af[mi] = *(const f16x8*)&AS[buf][wm][rh * 64 + c2 * 8];
            }
            __builtin_amdgcn_s_setprio(1);
#pragma unroll
            for (int mi = 0; mi < 8; ++mi)
#pragma unroll
                for (int ni = 0; ni < 4; ++ni)
                    acc[mi][ni] = __builtin_amdgcn_mfma_f32_16x16x32_f16(af[mi], bf[ni], acc[mi][ni], 0, 0, 0);
            __builtin_amdgcn_s_setprio(0);
        }
    };

    STAGE(0, 0);
    STAGE(1, 1);
    asm volatile("s_waitcnt vmcnt(8)" ::: "memory");
    __builtin_amdgcn_sched_barrier(0);
    __builtin_amdgcn_s_barrier();

    for (int t = 0; t < NT; ++t) {
        int buf = t & 1;
        COMPUTE(buf);
        __builtin_amdgcn_s_barrier();
        if (t + 2 < NT) {
            STAGE(t + 2, buf);
            asm volatile("s_waitcnt vmcnt(8)" ::: "memory");
        } else {
            asm volatile("s_waitcnt vmcnt(0)" ::: "memory");
        }
        __builtin_amdgcn_sched_barrier(0);
        __builtin_amdgcn_s_barrier();
    }

#pragma unroll
    for (int mi = 0; mi < 8; ++mi) {
#pragma unroll
        for (int ni = 0; ni < 4; ++ni) {
#pragma unroll
            for (int j = 0; j < 4; ++j) {
                int r = bm + wm * 128 + mi * 16 + lhi * 4 + j;
                int c = bn + wn * 64 + ni * 16 + l16;
                u16 hv = f2h(acc[mi][ni][j]);
                int b = r >> 11, s = r & 2047;
                if (c < 2048) {
                    int hh = c >> 7, d = c & 127;
                    qo[(((size_t)(b * 16 + hh)) * 2048 + s) * 128 + d] = hv;
                } else if (c < 3072) {
                    int hh = (c - 2048) >> 7, d = c & 127;
                    ko[(((size_t)(b * 8 + hh)) * 2048 + s) * 128 + d] = hv;
                } else {
                    int hh = (c - 3072) >> 7, d = c & 127;
                    vto[(((size_t)(b * 8 + hh)) * 128 + d) * 2048 + s] = hv;
                }
            }
        }
    }
}

// ---------------- Output projection, 256x128 tile, BK=64, 8 waves, counted-vmcnt + XCD swizzle ----
__global__ __launch_bounds__(512, 1) void gemm8_op(
    const u16* __restrict__ A, const u16* __restrict__ Bw, float* __restrict__ Cf) {
    __shared__ alignas(16) u16 AS[2][2][128 * 64];
    __shared__ alignas(16) u16 BS[2][128 * 64];
    const int K = 2048, NT = 32;
    int tid = threadIdx.x;
    int wid = tid >> 6, lane = tid & 63;
    int l16 = lane & 15, lhi = lane >> 4;
    int wm = wid >> 2, wn = wid & 3;
    int bid = blockIdx.y * 16 + blockIdx.x;
    int swz = (bid & 7) * 32 + (bid >> 3);
    int bm = (swz >> 4) * 256, bn = (swz & 15) * 128;
    int srow = lane >> 3;
    int schunk = (lane & 7) ^ srow;
    f32x4 acc[8][2] = {};

    auto STAGE = [&](int t, int buf) {
        int kt = t * 64;
#pragma unroll
        for (int i = 0; i < 2; ++i) {
            int c = wid * 2 + i;
            int row = c * 8 + srow;
            const u16* sa0 = A + (size_t)(bm + row) * K + kt + schunk * 8;
            GLDS16(sa0, &AS[buf][0][c * 512]);
            const u16* sa1 = A + (size_t)(bm + 128 + row) * K + kt + schunk * 8;
            GLDS16(sa1, &AS[buf][1][c * 512]);
            const u16* sb0 = Bw + (size_t)(bn + row) * K + kt + schunk * 8;
            GLDS16(sb0, &BS[buf][c * 512]);
        }
    };

    auto COMPUTE = [&](int buf) {
#pragma unroll
        for (int kk = 0; kk < 2; ++kk) {
            f16x8 af[8], bf[2];
#pragma unroll
            for (int ni = 0; ni < 2; ++ni) {
                int rb = wn * 32 + ni * 16 + l16;
                int c2 = (kk * 4 + lhi) ^ (rb & 7);
                bf[ni] = *(const f16x8*)&BS[buf][rb * 64 + c2 * 8];
            }
#pragma unroll
            for (int mi = 0; mi < 8; ++mi) {
                int rh = mi * 16 + l16;
                int c2 = (kk * 4 + lhi) ^ (rh & 7);
                af[mi] = *(const f16x8*)&AS[buf][wm][rh * 64 + c2 * 8];
            }
            __builtin_amdgcn_s_setprio(1);
#pragma unroll
            for (int mi = 0; mi < 8; ++mi)
#pragma unroll
                for (int ni = 0; ni < 2; ++ni)
                    acc[mi][ni] = __builtin_amdgcn_mfma_f32_16x16x32_f16(af[mi], bf[ni], acc[mi][ni], 0, 0, 0);
            __builtin_amdgcn_s_setprio(0);
        }
    };

    STAGE(0, 0);
    STAGE(1, 1);
    asm volatile("s_waitcnt vmcnt(6)" ::: "memory");
    __builtin_amdgcn_sched_barrier(0);
    __builtin_amdgcn_s_barrier();

    for (int t = 0; t < NT; ++t) {
        int buf = t & 1;
        COMPUTE(buf);
        __builtin_amdgcn_s_barrier();
        if (t + 2 < NT) {
            STAGE(t + 2, buf);
            asm volatile("s_waitcnt vmcnt(6)" ::: "memory");
        } else {
            asm volatile("s_waitcnt vmcnt(0)" ::: "memory");
        }
        __builtin_amdgcn_sched_barrier(0);
        __builtin_amdgcn_s_barrier();
    }

#pragma unroll
    for (int mi = 0; mi < 8; ++mi)
#pragma unroll
        for (int ni = 0; ni < 2; ++ni)
#pragma unroll
            for (int j = 0; j < 4; ++j) {
                int r = bm + wm * 128 + mi * 16 + lhi * 4 + j;
                int c = bn + wn * 32 + ni * 16 + l16;
                Cf[(size_t)r * 2048 + c] = acc[mi][ni][j];
            }
}

// ---------------- RoPE fused q+k, vectorized: 8 d-elems/thread, u16x8 I/O (R18) ----------------
// Per-element math identical to the scalar version -> bit-identical q/k.
__global__ void rope_fused(u16* __restrict__ q, u16* __restrict__ k,
                           const float* __restrict__ cosv, const float* __restrict__ sinv) {
    int i = blockIdx.x * 128 + threadIdx.x;   // 32768 threads = 2*2048*8
    int d8 = (i & 7) * 8;                     // d-octet 0..56
    int s = (i >> 3) & 2047;
    int b = i >> 14;
    size_t cb = ((size_t)b * 2048 + s) * 128;
    float c1[8], s1[8], c2[8], s2[8];
    *(f32x4*)&c1[0] = *(const f32x4*)&cosv[cb + d8];
    *(f32x4*)&c1[4] = *(const f32x4*)&cosv[cb + d8 + 4];
    *(f32x4*)&s1[0] = *(const f32x4*)&sinv[cb + d8];
    *(f32x4*)&s1[4] = *(const f32x4*)&sinv[cb + d8 + 4];
    *(f32x4*)&c2[0] = *(const f32x4*)&cosv[cb + d8 + 64];
    *(f32x4*)&c2[4] = *(const f32x4*)&cosv[cb + d8 + 68];
    *(f32x4*)&s2[0] = *(const f32x4*)&sinv[cb + d8 + 64];
    *(f32x4*)&s2[4] = *(const f32x4*)&sinv[cb + d8 + 68];
#pragma unroll
    for (int h = 0; h < 16; ++h) {
        size_t base = (((size_t)(b * 16 + h)) * 2048 + s) * 128;
        u16x8 x1v = *(const u16x8*)&q[base + d8];
        u16x8 x2v = *(const u16x8*)&q[base + d8 + 64];
        u16x8 o1, o2;
#pragma unroll
        for (int e = 0; e < 8; ++e) {
            float x1 = h2f(x1v[e]), x2 = h2f(x2v[e]);
            o1[e] = f2h(x1 * c1[e] - x2 * s1[e]);
            o2[e] = f2h(x2 * c2[e] + x1 * s2[e]);
        }
        *(u16x8*)&q[base + d8] = o1;
        *(u16x8*)&q[base + d8 + 64] = o2;
    }
#pragma unroll
    for (int h = 0; h < 8; ++h) {
        size_t base = (((size_t)(b * 8 + h)) * 2048 + s) * 128;
        u16x8 x1v = *(const u16x8*)&k[base + d8];
        u16x8 x2v = *(const u16x8*)&k[base + d8 + 64];
        u16x8 o1, o2;
#pragma unroll
        for (int e = 0; e < 8; ++e) {
            float x1 = h2f(x1v[e]), x2 = h2f(x2v[e]);
            o1[e] = f2h(x1 * c1[e] - x2 * s1[e]);
            o2[e] = f2h(x2 * c2[e] + x1 * s2[e]);
        }
        *(u16x8*)&k[base + d8] = o1;
        *(u16x8*)&k[base + d8 + 64] = o2;
    }
}

// ---------------- Wdtv = Wdt (16x1024) @ Wv (1024x2048), f32 ----------------
__global__ void wdtv_kernel(const float* __restrict__ Wdt, const float* __restrict__ Wv,
                            float* __restrict__ out) {
    int t = threadIdx.x;
    int h = blockIdx.x >> 3;
    int c = (blockIdx.x & 7) * 256 + t;
    const float* wd = Wdt + h * 1024;
    float acc = 0.f;
    for (int f = 0; f < 1024; ++f) acc += wd[f] * Wv[(size_t)f * 2048 + c];
    out[h * 2048 + c] = acc;
}

// ---------------- dt = x @ Wdtv^T ; dyn = exp(A*softplus(dt)) ----------------
__global__ void dt_dyn_kernel(const float* __restrict__ x, const float* __restrict__ Wdtv,
                              const float* __restrict__ Av, float* __restrict__ dyn) {
    __shared__ float xrow[2048];
    __shared__ float red[256];
    int bs = blockIdx.x;
    int t = threadIdx.x;
    for (int i = t; i < 2048; i += 256) xrow[i] = x[(size_t)bs * 2048 + i];
    __syncthreads();
    int h = t & 15, chunk = t >> 4;
    float p = 0.f;
    const float* wrow = Wdtv + h * 2048 + chunk * 128;
    const float* xr = xrow + chunk * 128;
    for (int f = 0; f < 128; ++f) p += xr[f] * wrow[f];
    red[t] = p;
    __syncthreads();
    if (t < 16) {
        float dt = 0.f;
        for (int c = 0; c < 16; ++c) dt += red[c * 16 + t];
        float sp = fmaxf(dt, 0.f) + log1pf(expf(-fabsf(dt)));
        int b = bs >> 11, s = bs & 2047;
        dyn[((size_t)(b * 16 + t)) * 2048 + s] = expf(Av[t] * sp);
    }
}

// ---------------- kth (1024th smallest of 2048) + mask values — bitonic ----------------
__global__ void kth_mask_kernel(const float* __restrict__ dyn, float* __restrict__ mval) {
    __shared__ float sv[2048];
    int bh = blockIdx.x, t = threadIdx.x;  // 1024 threads
    const float* row = dyn + (size_t)bh * 2048;
    sv[t] = row[t];
    sv[t + 1024] = row[t + 1024];
    __syncthreads();
    for (int k = 2; k <= 2048; k <<= 1) {
        for (int j = k >> 1; j > 0; j >>= 1) {
#pragma unroll 1
            for (int base = 0; base < 2048; base += 1024) {
                int i = base + t;
                int ixj = i ^ j;
                if (ixj > i) {
                    float a = sv[i], b = sv[ixj];
                    bool up = ((i & k) == 0);
                    if ((a > b) == up) { sv[i] = b; sv[ixj] = a; }
                }
            }
            __syncthreads();
        }
    }
    float kth = sv[1023];
    float v0 = row[t];
    float v1 = row[t + 1024];
    mval[(size_t)bh * 2048 + t] = v0 < kth ? MINF : v0;
    mval[(size_t)bh * 2048 + t + 1024] = v1 < kth ? MINF : v1;
}

// ---------------- flash attention (R13-exact: KVBLK=64, K+V staged, P stride 72) ----------------
__global__ __launch_bounds__(256) void attn_kernel(
    const u16* __restrict__ qb, const u16* __restrict__ kb, const u16* __restrict__ vtb,
    const float* __restrict__ mv, u16* __restrict__ ao) {
    __shared__ alignas(16) u16 Kst[2][64 * 128];
    __shared__ alignas(16) u16 Vst[2][128 * 64];
    __shared__ alignas(16) u16 plds[4][16 * 72];
    __shared__ int flags[4];
    int bh = blockIdx.x;
    int qt = 31 - blockIdx.y;
    int b = bh >> 4, h = bh & 15, kvh = h >> 1;
    int wid = threadIdx.x >> 6, lane = threadIdx.x & 63;
    int l16 = lane & 15, lhi = lane >> 4;
    int q0 = qt * 64 + wid * 16;
    const u16* qbase = qb + (((size_t)bh * 2048) + q0) * 128;
    const u16* kbase = kb + ((size_t)(b * 8 + kvh) * 2048) * 128;
    const u16* vtbase = vtb + ((size_t)(b * 8 + kvh) * 128) * 2048;
    const float* mvb = mv + (size_t)bh * 2048;
    u16* pw = plds[wid];
    int rx = l16 & 7;

    auto STAGE = [&](int kt2, int bidx) {
        int kvb2 = kt2 * 64;
#pragma unroll
        for (int i = 0; i < 4; ++i) {
            int call = wid * 4 + i;
            int r = call * 4 + (lane >> 4);
            int gch = (lane & 15) ^ (r & 7);
            const u16* src = kbase + (size_t)(kvb2 + r) * 128 + gch * 8;
            GLDS16(src, &Kst[bidx][call * 512]);
        }
#pragma unroll
        for (int i = 0; i < 4; ++i) {
            int call = wid * 4 + i;
            int d = call * 8 + (lane >> 3);
            int gch = (lane & 7) ^ (d & 7);
            const u16* src = vtbase + (size_t)d * 2048 + kvb2 + gch * 8;
            GLDS16(src, &Vst[bidx][call * 512]);
        }
    };

    f16x8 qf[4];
#pragma unroll
    for (int kc = 0; kc < 4; ++kc) qf[kc] = *(const f16x8*)&qbase[l16 * 128 + kc * 32 + lhi * 8];
    f16x8 ones;
#pragma unroll
    for (int i = 0; i < 8; ++i) ones[i] = (_Float16)1.f;
    float m[4];
#pragma unroll
    for (int j = 0; j < 4; ++j) m[j] = -INFINITY;
    f32x4 accO[8] = {};
    f32x4 accS = {};

    STAGE(0, 0);
    __syncthreads();

    for (int kt = 0; kt < 32; ++kt) {
        if (kt > qt) {
            if (!(flags[0] | flags[1] | flags[2] | flags[3])) break;
        }
        int buf = kt & 1;
        if (kt + 1 < 32) STAGE(kt + 1, buf ^ 1);
        int kvb = kt * 64;

        f32x4 sc[4] = {};
#pragma unroll
        for (int ni = 0; ni < 4; ++ni) {
            const u16* kr = &Kst[buf][(ni * 16 + l16) * 128];
#pragma unroll
            for (int kc = 0; kc < 4; ++kc) {
                int cc = (kc * 4 + lhi) ^ rx;
                f16x8 kf = *(const f16x8*)&kr[cc * 8];
                sc[ni] = __builtin_amdgcn_mfma_f32_16x16x32_f16(qf[kc], kf, sc[ni], 0, 0, 0);
            }
        }

        float rmax[4] = {-INFINITY, -INFINITY, -INFINITY, -INFINITY};
#pragma unroll
        for (int ni = 0; ni < 4; ++ni) {
            int key = kvb + ni * 16 + l16;
            float mk = mvb[key];
#pragma unroll
            for (int j = 0; j < 4; ++j) {
                int qrow = q0 + lhi * 4 + j;
                // exact reference arithmetic: mask = dynmask + causalMIN (f32, may -> -inf),
                // then score = qk*scale + mask (MIN absorbs qk*scale exactly).
                float sval = sc[ni][j] * SCALE + (mk + (key > qrow ? MINF : 0.f));
                sc[ni][j] = sval;
                rmax[j] = fmaxf(rmax[j], sval);
            }
        }
#pragma unroll
        for (int j = 0; j < 4; ++j) {
#pragma unroll
            for (int off = 1; off < 16; off <<= 1) rmax[j] = fmaxf(rmax[j], __shfl_xor(rmax[j], off));
        }
        float mn[4];
        bool need = false;
#pragma unroll
        for (int j = 0; j < 4; ++j) {
            mn[j] = fmaxf(m[j], rmax[j]);
            need |= (mn[j] - m[j] > 8.0f);
        }
        if (__any(need)) {
#pragma unroll
            for (int j = 0; j < 4; ++j) {
                float r = __expf(m[j] - mn[j]);
                m[j] = mn[j];
                accS[j] *= r;
#pragma unroll
                for (int db = 0; db < 8; ++db) accO[db][j] *= r;
            }
        }
#pragma unroll
        for (int ni = 0; ni < 4; ++ni) {
#pragma unroll
            for (int j = 0; j < 4; ++j) {
                float pv = __expf(sc[ni][j] - m[j]);
                pw[(lhi * 4 + j) * 72 + ni * 16 + l16] = f2h(pv);
            }
        }

#pragma unroll
        for (int kc2 = 0; kc2 < 2; ++kc2) {
            f16x8 pa = *(const f16x8*)&pw[l16 * 72 + kc2 * 32 + lhi * 8];
            accS = __builtin_amdgcn_mfma_f32_16x16x32_f16(pa, ones, accS, 0, 0, 0);
#pragma unroll
            for (int db = 0; db < 8; ++db) {
                int cc = (kc2 * 4 + lhi) ^ rx;
                f16x8 vf = *(const f16x8*)&Vst[buf][(db * 16 + l16) * 64 + cc * 8];
                accO[db] = __builtin_amdgcn_mfma_f32_16x16x32_f16(pa, vf, accO[db], 0, 0, 0);
            }
        }

        bool deg = (m[0] == MINF) | (m[1] == MINF) | (m[2] == MINF) | (m[3] == MINF);
        if (lane == 0) flags[wid] = __any(deg) ? 1 : 0;
        __syncthreads();
    }

#pragma unroll
    for (int db = 0; db < 8; ++db) {
#pragma unroll
        for (int j = 0; j < 4; ++j) {
            int qrow = q0 + lhi * 4 + j;
            int d = db * 16 + l16;
            float o = accO[db][j] / accS[j];
            ao[((size_t)(b * 2048) + qrow) * 2048 + h * 128 + d] = f2h(o);
        }
    }
}

extern "C" void kernel_launch(void* const* d_in, const int* in_sizes, int n_in,
                              void* d_out, int out_size, void* d_ws, size_t ws_size,
                              hipStream_t stream) {
    const float* x = (const float*)d_in[0];
    const float* cosv = (const float*)d_in[1];
    const float* sinv = (const float*)d_in[2];
    const float* Wq = (const float*)d_in[4];
    const float* Wk = (const float*)d_in[5];
    const float* Wv = (const float*)d_in[6];
    const float* Av = (const float*)d_in[7];
    const float* Wdt = (const float*)d_in[8];
    const float* Wo = (const float*)d_in[9];

    char* ws = (char*)d_ws;
    u16* qb = (u16*)(ws);
    u16* kb = (u16*)(ws + 16777216);
    u16* vtb = (u16*)(ws + 25165824);
    float* dyn = (float*)(ws + 33554432);
    float* mval = (float*)(ws + 33816576);
    float* wdtv = (float*)(ws + 34078720);
    u16* xbf = (u16*)(ws + 34209792);
    u16* wbf = (u16*)(ws + 50987008);

    // 1. conversions to f16
    convk8<<<8388608 / 2048, 256, 0, stream>>>(x, xbf, 8388608);
    convw3<<<8388608 / 2048, 256, 0, stream>>>(Wq, Wk, Wv, wbf);

    // 2. fused QKV GEMM (XCD-swizzled)
    dim3 g1(16, 16);
    gemm8_qkv<<<g1, 512, 0, stream>>>(xbf, wbf, qb, kb, vtb);

    // 3. RoPE fused q+k (vectorized u16x8)
    rope_fused<<<256, 128, 0, stream>>>(qb, kb, cosv, sinv);

    // 4. dynamic mask path (f32-exact dt; bitonic kth)
    wdtv_kernel<<<128, 256, 0, stream>>>(Wdt, Wv, wdtv);
    dt_dyn_kernel<<<4096, 256, 0, stream>>>(x, wdtv, Av, dyn);
    kth_mask_kernel<<<32, 1024, 0, stream>>>(dyn, mval);

    // 5. Wo -> f16
    convk8<<<4194304 / 2048, 256, 0, stream>>>(Wo, wbf, 4194304);

    // 6. attention (KVBLK=64, P stride 72)
    dim3 g2(32, 32);
    attn_kernel<<<g2, 256, 0, stream>>>(qb, kb, vtb, mval, xbf);

    // 7. output projection (XCD-swizzled) -> f32 d_out
    dim3 g3(16, 16);
    gemm8_op<<<g3, 512, 0, stream>>>(xbf, wbf, (float*)d_out);
}

// Round 22
// 424.841 us; speedup vs baseline: 1.0508x; 1.0508x over previous
//
#include <hip/hip_runtime.h>

typedef unsigned short u16;
typedef _Float16 f16x8 __attribute__((ext_vector_type(8)));
typedef float f32x4 __attribute__((ext_vector_type(4)));
typedef u16 u16x8 __attribute__((ext_vector_type(8)));
typedef u16 u16x4 __attribute__((ext_vector_type(4)));

#define MINF (-0x1.fffffep+127f)
#define SCALE 0.08838834764831845f

__device__ __forceinline__ u16 f2h(float f) {
    _Float16 h = (_Float16)f;
    return __builtin_bit_cast(u16, h);
}
__device__ __forceinline__ float h2f(u16 u) {
    _Float16 h = __builtin_bit_cast(_Float16, u);
    return (float)h;
}

typedef const __attribute__((address_space(1))) void* gptr_t;
typedef __attribute__((address_space(3))) void* sptr_t;
#define GLDS16(g, l) __builtin_amdgcn_global_load_lds((gptr_t)(const void*)(g), (sptr_t)(void*)(l), 16, 0, 0)

// ---------------- f32 -> f16 conversion, 8 elem/thread (n must be divisible by 2048) ----------------
__global__ void convk8(const float* __restrict__ in, u16* __restrict__ out, int n) {
    int i = (blockIdx.x * 256 + threadIdx.x) * 8;
    if (i >= n) return;
    f32x4 a = *(const f32x4*)&in[i];
    f32x4 b = *(const f32x4*)&in[i + 4];
    u16x8 r;
#pragma unroll
    for (int j = 0; j < 4; ++j) { r[j] = f2h(a[j]); r[j + 4] = f2h(b[j]); }
    *(u16x8*)&out[i] = r;
}

// ---------------- fused Wq/Wk/Wv -> f16 into contiguous wbf ----------------
__global__ void convw3(const float* __restrict__ Wq, const float* __restrict__ Wk,
                       const float* __restrict__ Wv, u16* __restrict__ out) {
    int i = (blockIdx.x * 256 + threadIdx.x) * 8;
    const float* src;
    int off;
    if (i < 4194304) { src = Wq; off = i; }
    else if (i < 6291456) { src = Wk; off = i - 4194304; }
    else { src = Wv; off = i - 6291456; }
    f32x4 a = *(const f32x4*)&src[off];
    f32x4 b = *(const f32x4*)&src[off + 4];
    u16x8 r;
#pragma unroll
    for (int j = 0; j < 4; ++j) { r[j] = f2h(a[j]); r[j + 4] = f2h(b[j]); }
    *(u16x8*)&out[i] = r;
}

// ---------------- QKV GEMM, 256x256 tile, BK=64, 8 waves, counted-vmcnt + XCD swizzle ----------------
__global__ __launch_bounds__(512, 1) void gemm8_qkv(
    const u16* __restrict__ A, const u16* __restrict__ Bw,
    u16* __restrict__ qo, u16* __restrict__ ko, u16* __restrict__ vto) {
    __shared__ alignas(16) u16 AS[2][2][128 * 64];
    __shared__ alignas(16) u16 BS[2][2][128 * 64];
    const int K = 2048, NT = 32;
    int tid = threadIdx.x;
    int wid = tid >> 6, lane = tid & 63;
    int l16 = lane & 15, lhi = lane >> 4;
    int wm = wid >> 2, wn = wid & 3;
    int bid = blockIdx.y * 16 + blockIdx.x;
    int swz = (bid & 7) * 32 + (bid >> 3);
    int bm = (swz >> 4) * 256, bn = (swz & 15) * 256;
    int srow = lane >> 3;
    int schunk = (lane & 7) ^ srow;
    f32x4 acc[8][4] = {};

    auto STAGE = [&](int t, int buf) {
        int kt = t * 64;
#pragma unroll
        for (int i = 0; i < 2; ++i) {
            int c = wid * 2 + i;
            int row = c * 8 + srow;
            const u16* sa0 = A + (size_t)(bm + row) * K + kt + schunk * 8;
            GLDS16(sa0, &AS[buf][0][c * 512]);
            const u16* sa1 = A + (size_t)(bm + 128 + row) * K + kt + schunk * 8;
            GLDS16(sa1, &AS[buf][1][c * 512]);
            const u16* sb0 = Bw + (size_t)(bn + row) * K + kt + schunk * 8;
            GLDS16(sb0, &BS[buf][0][c * 512]);
            const u16* sb1 = Bw + (size_t)(bn + 128 + row) * K + kt + schunk * 8;
            GLDS16(sb1, &BS[buf][1][c * 512]);
        }
    };

    auto COMPUTE = [&](int buf) {
#pragma unroll
        for (int kk = 0; kk < 2; ++kk) {
            f16x8 af[8], bf[4];
#pragma unroll
            for (int ni = 0; ni < 4; ++ni) {
                int rb = wn * 64 + ni * 16 + l16;
                int half = rb >> 7, rh = rb & 127;
                int c2 = (kk * 4 + lhi) ^ (rh & 7);
                bf[ni] = *(const f16x8*)&BS[buf][half][rh * 64 + c2 * 8];
            }
#pragma unroll
            for (int mi = 0; mi < 8; ++mi) {
                int rh = mi * 16 + l16;
                int c2 = (kk * 4 + lhi) ^ (rh & 7);
                af[mi] = *(const f16x8*)&AS[buf][wm][rh * 64 + c2 * 8];
            }
            __builtin_amdgcn_s_setprio(1);
#pragma unroll
            for (int mi = 0; mi < 8; ++mi)
#pragma unroll
                for (int ni = 0; ni < 4; ++ni)
                    acc[mi][ni] = __builtin_amdgcn_mfma_f32_16x16x32_f16(af[mi], bf[ni], acc[mi][ni], 0, 0, 0);
            __builtin_amdgcn_s_setprio(0);
        }
    };

    STAGE(0, 0);
    STAGE(1, 1);
    asm volatile("s_waitcnt vmcnt(8)" ::: "memory");
    __builtin_amdgcn_sched_barrier(0);
    __builtin_amdgcn_s_barrier();

    for (int t = 0; t < NT; ++t) {
        int buf = t & 1;
        COMPUTE(buf);
        __builtin_amdgcn_s_barrier();
        if (t + 2 < NT) {
            STAGE(t + 2, buf);
            asm volatile("s_waitcnt vmcnt(8)" ::: "memory");
        } else {
            asm volatile("s_waitcnt vmcnt(0)" ::: "memory");
        }
        __builtin_amdgcn_sched_barrier(0);
        __builtin_amdgcn_s_barrier();
    }

#pragma unroll
    for (int mi = 0; mi < 8; ++mi) {
#pragma unroll
        for (int ni = 0; ni < 4; ++ni) {
#pragma unroll
            for (int j = 0; j < 4; ++j) {
                int r = bm + wm * 128 + mi * 16 + lhi * 4 + j;
                int c = bn + wn * 64 + ni * 16 + l16;
                u16 hv = f2h(acc[mi][ni][j]);
                int b = r >> 11, s = r & 2047;
                if (c < 2048) {
                    int hh = c >> 7, d = c & 127;
                    qo[(((size_t)(b * 16 + hh)) * 2048 + s) * 128 + d] = hv;
                } else if (c < 3072) {
                    int hh = (c - 2048) >> 7, d = c & 127;
                    ko[(((size_t)(b * 8 + hh)) * 2048 + s) * 128 + d] = hv;
                } else {
                    int hh = (c - 3072) >> 7, d = c & 127;
                    vto[(((size_t)(b * 8 + hh)) * 128 + d) * 2048 + s] = hv;
                }
            }
        }
    }
}

// ---------------- Output projection, 256x128 tile, BK=64, 8 waves, counted-vmcnt + XCD swizzle ----
__global__ __launch_bounds__(512, 1) void gemm8_op(
    const u16* __restrict__ A, const u16* __restrict__ Bw, float* __restrict__ Cf) {
    __shared__ alignas(16) u16 AS[2][2][128 * 64];
    __shared__ alignas(16) u16 BS[2][128 * 64];
    const int K = 2048, NT = 32;
    int tid = threadIdx.x;
    int wid = tid >> 6, lane = tid & 63;
    int l16 = lane & 15, lhi = lane >> 4;
    int wm = wid >> 2, wn = wid & 3;
    int bid = blockIdx.y * 16 + blockIdx.x;
    int swz = (bid & 7) * 32 + (bid >> 3);
    int bm = (swz >> 4) * 256, bn = (swz & 15) * 128;
    int srow = lane >> 3;
    int schunk = (lane & 7) ^ srow;
    f32x4 acc[8][2] = {};

    auto STAGE = [&](int t, int buf) {
        int kt = t * 64;
#pragma unroll
        for (int i = 0; i < 2; ++i) {
            int c = wid * 2 + i;
            int row = c * 8 + srow;
            const u16* sa0 = A + (size_t)(bm + row) * K + kt + schunk * 8;
            GLDS16(sa0, &AS[buf][0][c * 512]);
            const u16* sa1 = A + (size_t)(bm + 128 + row) * K + kt + schunk * 8;
            GLDS16(sa1, &AS[buf][1][c * 512]);
            const u16* sb0 = Bw + (size_t)(bn + row) * K + kt + schunk * 8;
            GLDS16(sb0, &BS[buf][c * 512]);
        }
    };

    auto COMPUTE = [&](int buf) {
#pragma unroll
        for (int kk = 0; kk < 2; ++kk) {
            f16x8 af[8], bf[2];
#pragma unroll
            for (int ni = 0; ni < 2; ++ni) {
                int rb = wn * 32 + ni * 16 + l16;
                int c2 = (kk * 4 + lhi) ^ (rb & 7);
                bf[ni] = *(const f16x8*)&BS[buf][rb * 64 + c2 * 8];
            }
#pragma unroll
            for (int mi = 0; mi < 8; ++mi) {
                int rh = mi * 16 + l16;
                int c2 = (kk * 4 + lhi) ^ (rh & 7);
                af[mi] = *(const f16x8*)&AS[buf][wm][rh * 64 + c2 * 8];
            }
            __builtin_amdgcn_s_setprio(1);
#pragma unroll
            for (int mi = 0; mi < 8; ++mi)
#pragma unroll
                for (int ni = 0; ni < 2; ++ni)
                    acc[mi][ni] = __builtin_amdgcn_mfma_f32_16x16x32_f16(af[mi], bf[ni], acc[mi][ni], 0, 0, 0);
            __builtin_amdgcn_s_setprio(0);
        }
    };

    STAGE(0, 0);
    STAGE(1, 1);
    asm volatile("s_waitcnt vmcnt(6)" ::: "memory");
    __builtin_amdgcn_sched_barrier(0);
    __builtin_amdgcn_s_barrier();

    for (int t = 0; t < NT; ++t) {
        int buf = t & 1;
        COMPUTE(buf);
        __builtin_amdgcn_s_barrier();
        if (t + 2 < NT) {
            STAGE(t + 2, buf);
            asm volatile("s_waitcnt vmcnt(6)" ::: "memory");
        } else {
            asm volatile("s_waitcnt vmcnt(0)" ::: "memory");
        }
        __builtin_amdgcn_sched_barrier(0);
        __builtin_amdgcn_s_barrier();
    }

#pragma unroll
    for (int mi = 0; mi < 8; ++mi)
#pragma unroll
        for (int ni = 0; ni < 2; ++ni)
#pragma unroll
            for (int j = 0; j < 4; ++j) {
                int r = bm + wm * 128 + mi * 16 + lhi * 4 + j;
                int c = bn + wn * 32 + ni * 16 + l16;
                Cf[(size_t)r * 2048 + c] = acc[mi][ni][j];
            }
}

// ---------------- RoPE fused q+k, vectorized ----------------
__global__ void rope_fused(u16* __restrict__ q, u16* __restrict__ k,
                           const float* __restrict__ cosv, const float* __restrict__ sinv) {
    int i = blockIdx.x * 128 + threadIdx.x;
    int d8 = (i & 7) * 8;
    int s = (i >> 3) & 2047;
    int b = i >> 14;
    size_t cb = ((size_t)b * 2048 + s) * 128;
    float c1[8], s1[8], c2[8], s2[8];
    *(f32x4*)&c1[0] = *(const f32x4*)&cosv[cb + d8];
    *(f32x4*)&c1[4] = *(const f32x4*)&cosv[cb + d8 + 4];
    *(f32x4*)&s1[0] = *(const f32x4*)&sinv[cb + d8];
    *(f32x4*)&s1[4] = *(const f32x4*)&sinv[cb + d8 + 4];
    *(f32x4*)&c2[0] = *(const f32x4*)&cosv[cb + d8 + 64];
    *(f32x4*)&c2[4] = *(const f32x4*)&cosv[cb + d8 + 68];
    *(f32x4*)&s2[0] = *(const f32x4*)&sinv[cb + d8 + 64];
    *(f32x4*)&s2[4] = *(const f32x4*)&sinv[cb + d8 + 68];
#pragma unroll
    for (int h = 0; h < 16; ++h) {
        size_t base = (((size_t)(b * 16 + h)) * 2048 + s) * 128;
        u16x8 x1v = *(const u16x8*)&q[base + d8];
        u16x8 x2v = *(const u16x8*)&q[base + d8 + 64];
        u16x8 o1, o2;
#pragma unroll
        for (int e = 0; e < 8; ++e) {
            float x1 = h2f(x1v[e]), x2 = h2f(x2v[e]);
            o1[e] = f2h(x1 * c1[e] - x2 * s1[e]);
            o2[e] = f2h(x2 * c2[e] + x1 * s2[e]);
        }
        *(u16x8*)&q[base + d8] = o1;
        *(u16x8*)&q[base + d8 + 64] = o2;
    }
#pragma unroll
    for (int h = 0; h < 8; ++h) {
        size_t base = (((size_t)(b * 8 + h)) * 2048 + s) * 128;
        u16x8 x1v = *(const u16x8*)&k[base + d8];
        u16x8 x2v = *(const u16x8*)&k[base + d8 + 64];
        u16x8 o1, o2;
#pragma unroll
        for (int e = 0; e < 8; ++e) {
            float x1 = h2f(x1v[e]), x2 = h2f(x2v[e]);
            o1[e] = f2h(x1 * c1[e] - x2 * s1[e]);
            o2[e] = f2h(x2 * c2[e] + x1 * s2[e]);
        }
        *(u16x8*)&k[base + d8] = o1;
        *(u16x8*)&k[base + d8 + 64] = o2;
    }
}

// ---------------- Wdtv = Wdt (16x1024) @ Wv (1024x2048), f32 ----------------
__global__ void wdtv_kernel(const float* __restrict__ Wdt, const float* __restrict__ Wv,
                            float* __restrict__ out) {
    int t = threadIdx.x;
    int h = blockIdx.x >> 3;
    int c = (blockIdx.x & 7) * 256 + t;
    const float* wd = Wdt + h * 1024;
    float acc = 0.f;
    for (int f = 0; f < 1024; ++f) acc += wd[f] * Wv[(size_t)f * 2048 + c];
    out[h * 2048 + c] = acc;
}

// ---------------- dt = x @ Wdtv^T ; dyn = exp(A*softplus(dt)) ----------------
__global__ void dt_dyn_kernel(const float* __restrict__ x, const float* __restrict__ Wdtv,
                              const float* __restrict__ Av, float* __restrict__ dyn) {
    __shared__ float xrow[2048];
    __shared__ float red[256];
    int bs = blockIdx.x;
    int t = threadIdx.x;
    for (int i = t; i < 2048; i += 256) xrow[i] = x[(size_t)bs * 2048 + i];
    __syncthreads();
    int h = t & 15, chunk = t >> 4;
    float p = 0.f;
    const float* wrow = Wdtv + h * 2048 + chunk * 128;
    const float* xr = xrow + chunk * 128;
    for (int f = 0; f < 128; ++f) p += xr[f] * wrow[f];
    red[t] = p;
    __syncthreads();
    if (t < 16) {
        float dt = 0.f;
        for (int c = 0; c < 16; ++c) dt += red[c * 16 + t];
        float sp = fmaxf(dt, 0.f) + log1pf(expf(-fabsf(dt)));
        int b = bs >> 11, s = bs & 2047;
        dyn[((size_t)(b * 16 + t)) * 2048 + s] = expf(Av[t] * sp);
    }
}

// ---------------- kth (1024th smallest of 2048) + mask values — bitonic ----------------
__global__ void kth_mask_kernel(const float* __restrict__ dyn, float* __restrict__ mval) {
    __shared__ float sv[2048];
    int bh = blockIdx.x, t = threadIdx.x;
    const float* row = dyn + (size_t)bh * 2048;
    sv[t] = row[t];
    sv[t + 1024] = row[t + 1024];
    __syncthreads();
    for (int k = 2; k <= 2048; k <<= 1) {
        for (int j = k >> 1; j > 0; j >>= 1) {
#pragma unroll 1
            for (int base = 0; base < 2048; base += 1024) {
                int i = base + t;
                int ixj = i ^ j;
                if (ixj > i) {
                    float a = sv[i], b = sv[ixj];
                    bool up = ((i & k) == 0);
                    if ((a > b) == up) { sv[i] = b; sv[ixj] = a; }
                }
            }
            __syncthreads();
        }
    }
    float kth = sv[1023];
    float v0 = row[t];
    float v1 = row[t + 1024];
    mval[(size_t)bh * 2048 + t] = v0 < kth ? MINF : v0;
    mval[(size_t)bh * 2048 + t + 1024] = v1 < kth ? MINF : v1;
}

// ---------------- flash attention: swapped QK^T (R20) ----------------
// sc = mfma(K, Q) -> C[key][qrow]: key = kvb+ni*16+lhi*4+j, qrow = q0+l16.
// Softmax key-reduction becomes lane-local + 2 shfl_xor; m/accS state is one
// scalar per lane (q-row = l16). P written TRANSPOSED back to [qrow][key]
// (4x ds_write_b64), so the PV side and epilogue are unchanged from R13.
__global__ __launch_bounds__(256) void attn_kernel(
    const u16* __restrict__ qb, const u16* __restrict__ kb, const u16* __restrict__ vtb,
    const float* __restrict__ mv, u16* __restrict__ ao) {
    __shared__ alignas(16) u16 Kst[2][64 * 128];
    __shared__ alignas(16) u16 Vst[2][128 * 64];
    __shared__ alignas(16) u16 plds[4][16 * 72];
    __shared__ int flags[4];
    int bh = blockIdx.x;
    int qt = 31 - blockIdx.y;
    int b = bh >> 4, h = bh & 15, kvh = h >> 1;
    int wid = threadIdx.x >> 6, lane = threadIdx.x & 63;
    int l16 = lane & 15, lhi = lane >> 4;
    int q0 = qt * 64 + wid * 16;
    int qrow1 = q0 + l16;                       // this lane's q-row (QK output col)
    const u16* qbase = qb + (((size_t)bh * 2048) + q0) * 128;
    const u16* kbase = kb + ((size_t)(b * 8 + kvh) * 2048) * 128;
    const u16* vtbase = vtb + ((size_t)(b * 8 + kvh) * 128) * 2048;
    const float* mvb = mv + (size_t)bh * 2048;
    u16* pw = plds[wid];
    int rx = l16 & 7;

    auto STAGE = [&](int kt2, int bidx) {
        int kvb2 = kt2 * 64;
#pragma unroll
        for (int i = 0; i < 4; ++i) {
            int call = wid * 4 + i;
            int r = call * 4 + (lane >> 4);
            int gch = (lane & 15) ^ (r & 7);
            const u16* src = kbase + (size_t)(kvb2 + r) * 128 + gch * 8;
            GLDS16(src, &Kst[bidx][call * 512]);
        }
#pragma unroll
        for (int i = 0; i < 4; ++i) {
            int call = wid * 4 + i;
            int d = call * 8 + (lane >> 3);
            int gch = (lane & 7) ^ (d & 7);
            const u16* src = vtbase + (size_t)d * 2048 + kvb2 + gch * 8;
            GLDS16(src, &Vst[bidx][call * 512]);
        }
    };

    f16x8 qf[4];
#pragma unroll
    for (int kc = 0; kc < 4; ++kc) qf[kc] = *(const f16x8*)&qbase[l16 * 128 + kc * 32 + lhi * 8];
    f16x8 ones;
#pragma unroll
    for (int i = 0; i < 8; ++i) ones[i] = (_Float16)1.f;
    float m1 = -INFINITY;                       // running max for q-row l16
    f32x4 accO[8] = {};
    f32x4 accS = {};

    STAGE(0, 0);
    __syncthreads();

    for (int kt = 0; kt < 32; ++kt) {
        if (kt > qt) {
            if (!(flags[0] | flags[1] | flags[2] | flags[3])) break;
        }
        int buf = kt & 1;
        if (kt + 1 < 32) STAGE(kt + 1, buf ^ 1);
        int kvb = kt * 64;

        // QK^T (swapped): mfma(kf, qf) -> C[key][qrow]
        f32x4 sc[4] = {};
#pragma unroll
        for (int ni = 0; ni < 4; ++ni) {
            const u16* kr = &Kst[buf][(ni * 16 + l16) * 128];
#pragma unroll
            for (int kc = 0; kc < 4; ++kc) {
                int cc = (kc * 4 + lhi) ^ rx;
                f16x8 kf = *(const f16x8*)&kr[cc * 8];
                sc[ni] = __builtin_amdgcn_mfma_f32_16x16x32_f16(kf, qf[kc], sc[ni], 0, 0, 0);
            }
        }

        // mask + lane-local max over this lane's 16 keys
        float lmax = -INFINITY;
#pragma unroll
        for (int ni = 0; ni < 4; ++ni) {
            f32x4 mk4 = *(const f32x4*)&mvb[kvb + ni * 16 + lhi * 4];
#pragma unroll
            for (int j = 0; j < 4; ++j) {
                int key = kvb + ni * 16 + lhi * 4 + j;
                // exact reference arithmetic: mask = dynmask + causalMIN (f32, may -> -inf),
                // then score = qk*scale + mask (MIN absorbs qk*scale exactly).
                float sval = sc[ni][j] * SCALE + (mk4[j] + (key > qrow1 ? MINF : 0.f));
                sc[ni][j] = sval;
                lmax = fmaxf(lmax, sval);
            }
        }
        // combine across the 4 lanes sharing this q-row
        lmax = fmaxf(lmax, __shfl_xor(lmax, 16));
        lmax = fmaxf(lmax, __shfl_xor(lmax, 32));
        float mn1 = fmaxf(m1, lmax);
        bool need = (mn1 - m1 > 8.0f);          // defer-max THR=8
        if (__any(need)) {
            float rl = __expf(m1 - mn1);        // exp(0)=1 for unchanged rows
            m1 = mn1;
            float r4[4];
#pragma unroll
            for (int j = 0; j < 4; ++j) r4[j] = __shfl(rl, lhi * 4 + j);
#pragma unroll
            for (int j = 0; j < 4; ++j) {
                accS[j] *= r4[j];
#pragma unroll
                for (int db = 0; db < 8; ++db) accO[db][j] *= r4[j];
            }
        }
        // P = exp(s - m), transposed write back to [qrow][key]
#pragma unroll
        for (int ni = 0; ni < 4; ++ni) {
            u16x4 pk;
#pragma unroll
            for (int j = 0; j < 4; ++j) pk[j] = f2h(__expf(sc[ni][j] - m1));
            *(u16x4*)&pw[l16 * 72 + ni * 16 + lhi * 4] = pk;
        }

        // PV (unchanged): P from LDS as A, V swizzled as B, + ones-column accS
#pragma unroll
        for (int kc2 = 0; kc2 < 2; ++kc2) {
            f16x8 pa = *(const f16x8*)&pw[l16 * 72 + kc2 * 32 + lhi * 8];
            accS = __builtin_amdgcn_mfma_f32_16x16x32_f16(pa, ones, accS, 0, 0, 0);
#pragma unroll
            for (int db = 0; db < 8; ++db) {
                int cc = (kc2 * 4 + lhi) ^ rx;
                f16x8 vf = *(const f16x8*)&Vst[buf][(db * 16 + l16) * 64 + cc * 8];
                accO[db] = __builtin_amdgcn_mfma_f32_16x16x32_f16(pa, vf, accO[db], 0, 0, 0);
            }
        }

        // deg nesting: any deg row in wave => row q0 (lane 0) deg, so lane-0 vote suffices
        bool deg = (m1 == MINF);
        if (lane == 0) flags[wid] = deg ? 1 : 0;
        __syncthreads();
    }

#pragma unroll
    for (int db = 0; db < 8; ++db) {
#pragma unroll
        for (int j = 0; j < 4; ++j) {
            int qrow = q0 + lhi * 4 + j;
            int d = db * 16 + l16;
            float o = accO[db][j] / accS[j];
            ao[((size_t)(b * 2048) + qrow) * 2048 + h * 128 + d] = f2h(o);
        }
    }
}

extern "C" void kernel_launch(void* const* d_in, const int* in_sizes, int n_in,
                              void* d_out, int out_size, void* d_ws, size_t ws_size,
                              hipStream_t stream) {
    const float* x = (const float*)d_in[0];
    const float* cosv = (const float*)d_in[1];
    const float* sinv = (const float*)d_in[2];
    const float* Wq = (const float*)d_in[4];
    const float* Wk = (const float*)d_in[5];
    const float* Wv = (const float*)d_in[6];
    const float* Av = (const float*)d_in[7];
    const float* Wdt = (const float*)d_in[8];
    const float* Wo = (const float*)d_in[9];

    char* ws = (char*)d_ws;
    u16* qb = (u16*)(ws);
    u16* kb = (u16*)(ws + 16777216);
    u16* vtb = (u16*)(ws + 25165824);
    float* dyn = (float*)(ws + 33554432);
    float* mval = (float*)(ws + 33816576);
    float* wdtv = (float*)(ws + 34078720);
    u16* xbf = (u16*)(ws + 34209792);
    u16* wbf = (u16*)(ws + 50987008);

    // 1. conversions to f16
    convk8<<<8388608 / 2048, 256, 0, stream>>>(x, xbf, 8388608);
    convw3<<<8388608 / 2048, 256, 0, stream>>>(Wq, Wk, Wv, wbf);

    // 2. fused QKV GEMM (XCD-swizzled)
    dim3 g1(16, 16);
    gemm8_qkv<<<g1, 512, 0, stream>>>(xbf, wbf, qb, kb, vtb);

    // 3. RoPE fused q+k (vectorized)
    rope_fused<<<256, 128, 0, stream>>>(qb, kb, cosv, sinv);

    // 4. dynamic mask path (f32-exact dt; bitonic kth)
    wdtv_kernel<<<128, 256, 0, stream>>>(Wdt, Wv, wdtv);
    dt_dyn_kernel<<<4096, 256, 0, stream>>>(x, wdtv, Av, dyn);
    kth_mask_kernel<<<32, 1024, 0, stream>>>(dyn, mval);

    // 5. Wo -> f16
    convk8<<<4194304 / 2048, 256, 0, stream>>>(Wo, wbf, 4194304);

    // 6. attention (swapped-QK^T softmax)
    dim3 g2(32, 32);
    attn_kernel<<<g2, 256, 0, stream>>>(qb, kb, vtb, mval, xbf);

    // 7. output projection (XCD-swizzled) -> f32 d_out
    dim3 g3(16, 16);
    gemm8_op<<<g3, 512, 0, stream>>>(xbf, wbf, (float*)d_out);
}